// Round 14
// baseline (156.466 us; speedup 1.0000x reference)
//
#include <hip/hip_runtime.h>
#include <hip/hip_bf16.h>
#include <stdint.h>

typedef __attribute__((ext_vector_type(8))) short bf16x8;
typedef __attribute__((ext_vector_type(4))) float f32x4v;
typedef __attribute__((ext_vector_type(16))) float f32x16;

#define CH_STRIDE 65536  // T*W*H

__device__ __forceinline__ uint16_t f2bf(float f) {
  uint32_t u = __builtin_bit_cast(uint32_t, f);
  u = (u + 0x7FFFu + ((u >> 16) & 1u)) >> 16;
  return (uint16_t)u;
}
__device__ __forceinline__ float bf2f(uint32_t b) {
  return __builtin_bit_cast(float, b << 16);
}
__device__ __forceinline__ uint16_t cvt_bf(float f) {
  return __builtin_bit_cast(uint16_t, __float2bfloat16(f));
}

#define MFMA32(a, b, c) __builtin_amdgcn_mfma_f32_32x32x16_bf16(a, b, c, 0, 0, 0)
#define LGKM0 asm volatile("s_waitcnt lgkmcnt(0)" ::: "memory")
#define BAR __builtin_amdgcn_s_barrier()
#define SCHED0 __builtin_amdgcn_sched_barrier(0)

#define LDSX_BYTES (6 * 8 * 66 * 16)  // 50688

__device__ __forceinline__ uint32_t swz(uint32_t b) {
  return b ^ (((b >> 7) & 7u) << 4);
}

__device__ __forceinline__ bf16x8 ldx(const uint8_t* ldsx, int r6, int oct, int ci) {
  return *(const bf16x8*)(ldsx + swz((uint32_t)((r6 * 8 + oct) * 66 + ci) * 16u));
}

// x staging unit: (r6, oct, colgroup g) -> 8 dwordx4 loads, 4 swizzled b128 writes
__device__ __forceinline__ void stage_unit(uint8_t* ldsx, const float* xs, int w0, int u) {
  int r6 = u >> 7, oct = (u >> 4) & 7, g = u & 15;
  int w = w0 - 1 + r6;
  uint32_t base = (uint32_t)((r6 * 8 + oct) * 66 + 4 * g + 1) * 16u;
  if ((unsigned)w < 64u) {
    const float* p = xs + (size_t)(oct * 8) * CH_STRIDE + w * 64 + 4 * g;
    f32x4v v[8];
    #pragma unroll
    for (int j = 0; j < 8; ++j) v[j] = *(const f32x4v*)(p + (size_t)j * CH_STRIDE);
    #pragma unroll
    for (int c = 0; c < 4; ++c) {
      bf16x8 frag;
      #pragma unroll
      for (int q = 0; q < 4; ++q) {
        frag[2 * q]     = (short)cvt_bf(v[2 * q][c]);
        frag[2 * q + 1] = (short)cvt_bf(v[2 * q + 1][c]);
      }
      *(bf16x8*)(ldsx + swz(base + (uint32_t)c * 16u)) = frag;
    }
  } else {
    bf16x8 z = {};
    #pragma unroll
    for (int c = 0; c < 4; ++c)
      *(bf16x8*)(ldsx + swz(base + (uint32_t)c * 16u)) = z;
  }
}
__device__ __forceinline__ void stage_halo(uint8_t* ldsx, int tid) {
  if (tid < 96) {
    int r6 = tid >> 4, rem = tid & 15;
    int oct = rem >> 1, side = rem & 1;
    bf16x8 z = {};
    *(bf16x8*)(ldsx + swz((uint32_t)((r6 * 8 + oct) * 66 + side * 65) * 16u)) = z;
  }
}
__device__ __forceinline__ void stage_x256(uint8_t* ldsx, const float* xs, int w0, int tid) {
  stage_halo(ldsx, tid);
  #pragma unroll
  for (int k = 0; k < 3; ++k) stage_unit(ldsx, xs, w0, tid + k * 256);
}
__device__ __forceinline__ void stage_x512(uint8_t* ldsx, const float* xs, int w0, int tid) {
  stage_halo(ldsx, tid);
  stage_unit(ldsx, xs, w0, tid);
  if (tid < 256) stage_unit(ldsx, xs, w0, 512 + tid);
}

__device__ __forceinline__ bf16x8 ldw_kv(const uint8_t* ldsw, int oct, int rowloc) {
  return *(const bf16x8*)(ldsw + (uint32_t)(oct * 128 + rowloc) * 16u);
}
__device__ __forceinline__ void ldw_g_kv2(bf16x8* r, const uint16_t* wkv, int tap, int tid) {
  #pragma unroll
  for (int k = 0; k < 2; ++k)
    r[k] = *(const bf16x8*)(wkv + ((size_t)tap * 1024 + tid + k * 512) * 8);
}
__device__ __forceinline__ void stw_kv2(uint8_t* ldsw, const bf16x8* r, int tid) {
  #pragma unroll
  for (int k = 0; k < 2; ++k)
    *(bf16x8*)(ldsw + (uint32_t)(tid + k * 512) * 16u) = r[k];
}

__device__ __forceinline__ bf16x8 ldw_q(const uint8_t* ldsw, int oct, int row) {
  return *(const bf16x8*)(ldsw + (uint32_t)(oct * 64 + row) * 16u);
}
__device__ __forceinline__ void ldw_g_q(bf16x8* r, const uint16_t* wq, int tap, int tid) {
  #pragma unroll
  for (int k = 0; k < 2; ++k)
    r[k] = *(const bf16x8*)(wq + ((size_t)tap * 512 + tid + k * 256) * 8);
}
__device__ __forceinline__ void stw_q(uint8_t* ldsw, const bf16x8* r, int tid) {
  #pragma unroll
  for (int k = 0; k < 2; ++k)
    *(bf16x8*)(ldsw + (uint32_t)(tid + k * 256) * 16u) = r[k];
}

// ---------------------------------------------------------------------------
__global__ void prep_weights(const float* __restrict__ wq, const float* __restrict__ wk,
                             const float* __restrict__ wv, uint16_t* __restrict__ wout) {
  int i = blockIdx.x * 256 + threadIdx.x;
  if (i >= 110592) return;
  if (i < 36864) {
    int tap = i >> 12, oct = (i >> 9) & 7, row = (i >> 3) & 63, j = i & 7;
    wout[i] = f2bf(wq[(row * 64 + oct * 8 + j) * 9 + tap]);
  } else {
    int m = i - 36864;
    int tap = m >> 13, oct = (m >> 10) & 7, rl = (m >> 3) & 127, j = m & 7;
    const float* src = (rl < 64) ? wk : wv;
    wout[i] = f2bf(src[((rl & 63) * 64 + oct * 8 + j) * 9 + tap]);
  }
}

// ---------------------------------------------------------------------------
// KV kernel: 512 thr / 8 waves = (ng row, mg channel-half). Each wave:
// acc 4xf32x16 (fits 4 waves/SIMD -> 16 waves/CU). Epilogue per R13.
// ---------------------------------------------------------------------------
__global__ __launch_bounds__(512, 4) void kv_s_kernel(
    const float* __restrict__ x, const uint16_t* __restrict__ wkv,
    const float* __restrict__ bk, const float* __restrict__ bv,
    float* __restrict__ s_out) {
  extern __shared__ uint8_t lds[];
  uint8_t* ldsx = lds;
  uint8_t* ldsw = lds + LDSX_BYTES;
  const int tid = threadIdx.x;
  const int l = tid & 63;
  const int wid = tid >> 6;
  const int ng = wid & 3, mg = wid >> 2;
  int bid = (int)(blockIdx.x & 7) * 256 + (int)(blockIdx.x >> 3);  // XCD swizzle
  const int rg = bid & 15, slice = bid >> 4;
  const int b = slice >> 4, t = slice & 15;
  const int w0 = rg * 4;
  const float* xs = x + ((size_t)b * 1024 + t) * 4096;
  const int lm = l & 31, lh = l >> 5;

  stage_x512(ldsx, xs, w0, tid);
  bf16x8 r[2];
  ldw_g_kv2(r, wkv, 0, tid);
  stw_kv2(ldsw, r, tid);
  ldw_g_kv2(r, wkv, 1, tid);   // tap1 in flight across the barrier
  SCHED0; LGKM0; BAR; SCHED0;

  f32x16 accK[2], accV[2];
  #pragma unroll
  for (int nt = 0; nt < 2; ++nt)
    #pragma unroll
    for (int q = 0; q < 16; ++q) { accK[nt][q] = 0.f; accV[nt][q] = 0.f; }

  #pragma unroll
  for (int tap = 0; tap < 9; ++tap) {
    const int dy = tap / 3, dx = tap % 3;
    __builtin_amdgcn_s_setprio(1);
    #pragma unroll
    for (int s = 0; s < 4; ++s) {
      int oct = s * 2 + lh;
      bf16x8 aK = ldw_kv(ldsw, oct, mg * 32 + lm);
      bf16x8 aV = ldw_kv(ldsw, oct, 64 + mg * 32 + lm);
      bf16x8 b0 = ldx(ldsx, ng + dy, oct, lm + dx);
      bf16x8 b1 = ldx(ldsx, ng + dy, oct, 32 + lm + dx);
      accK[0] = MFMA32(aK, b0, accK[0]);
      accK[1] = MFMA32(aK, b1, accK[1]);
      accV[0] = MFMA32(aV, b0, accV[0]);
      accV[1] = MFMA32(aV, b1, accV[1]);
    }
    __builtin_amdgcn_s_setprio(0);
    if (tap < 8) {
      SCHED0; BAR;
      stw_kv2(ldsw, r, tid);
      if (tap < 7) ldw_g_kv2(r, wkv, tap + 2, tid);
      SCHED0; LGKM0; BAR; SCHED0;
    }
  }

  // epilogue: LDS partial-dump, 64-thread reduce, 1 atomic per channel
  __syncthreads();                 // ldsx/ldsw dead
  float* red = (float*)lds;        // [c 64][132]
  #pragma unroll
  for (int q = 0; q < 16; ++q) {
    int cl = (q & 3) + 8 * (q >> 2) + 4 * lh;
    int c = mg * 32 + cl;
    float bkc = bk[c], bvc = bv[c];
    float p = (accK[0][q] + bkc) * (accV[0][q] + bvc)
            + (accK[1][q] + bkc) * (accV[1][q] + bvc);
    red[c * 132 + ng * 32 + lm] = p;
  }
  __syncthreads();
  if (tid < 64) {
    const f32x4v* rp = (const f32x4v*)(red + tid * 132);
    f32x4v a4 = {0.f, 0.f, 0.f, 0.f};
    #pragma unroll
    for (int j = 0; j < 32; ++j) a4 += rp[j];
    atomicAdd(s_out + (b * 16 + t) * 64 + tid, a4[0] + a4[1] + a4[2] + a4[3]);
  }
}

// ---------------------------------------------------------------------------
// Q kernel (R13, unchanged).
// ---------------------------------------------------------------------------
__global__ __launch_bounds__(256, 2) void q_out_kernel(
    const float* __restrict__ x, const uint16_t* __restrict__ wq,
    const float* __restrict__ bq, const float* __restrict__ s_in,
    const float* __restrict__ gamma, float* __restrict__ out) {
  extern __shared__ uint8_t lds[];
  uint8_t* ldsx = lds;
  uint8_t* ldsw = lds + LDSX_BYTES;
  const int tid = threadIdx.x;
  const int l = tid & 63, ng = tid >> 6;
  int bid = (int)(blockIdx.x & 7) * 256 + (int)(blockIdx.x >> 3);  // XCD swizzle
  const int rg = bid & 15, slice = bid >> 4;
  const int b = slice >> 4, t = slice & 15;
  const int w0 = rg * 4;
  const float* xs = x + ((size_t)b * 1024 + t) * 4096;
  const int lm = l & 31, lh = l >> 5;

  stage_x256(ldsx, xs, w0, tid);
  bf16x8 r[2];
  ldw_g_q(r, wq, 0, tid);
  stw_q(ldsw, r, tid);
  ldw_g_q(r, wq, 1, tid);
  SCHED0; LGKM0; BAR; SCHED0;

  f32x16 acc[2][2];
  #pragma unroll
  for (int mt = 0; mt < 2; ++mt)
    #pragma unroll
    for (int nt = 0; nt < 2; ++nt)
      #pragma unroll
      for (int q = 0; q < 16; ++q) acc[mt][nt][q] = 0.f;

  #pragma unroll
  for (int tap = 0; tap < 9; ++tap) {
    const int dy = tap / 3, dx = tap % 3;
    __builtin_amdgcn_s_setprio(1);
    #pragma unroll
    for (int s = 0; s < 4; ++s) {
      int oct = s * 2 + lh;
      bf16x8 a0 = ldw_q(ldsw, oct, lm);
      bf16x8 a1 = ldw_q(ldsw, oct, 32 + lm);
      bf16x8 b0 = ldx(ldsx, ng + dy, oct, lm + dx);
      bf16x8 b1 = ldx(ldsx, ng + dy, oct, 32 + lm + dx);
      acc[0][0] = MFMA32(a0, b0, acc[0][0]);
      acc[0][1] = MFMA32(a0, b1, acc[0][1]);
      acc[1][0] = MFMA32(a1, b0, acc[1][0]);
      acc[1][1] = MFMA32(a1, b1, acc[1][1]);
    }
    __builtin_amdgcn_s_setprio(0);
    if (tap < 8) {
      SCHED0; BAR;
      stw_q(ldsw, r, tid);
      if (tap < 7) ldw_g_q(r, wq, tap + 2, tid);
      SCHED0; LGKM0; BAR; SCHED0;
    }
  }

  float g = gamma[0];
  const float* sb = s_in + (b * 16 + t) * 64;
  int w = w0 + ng;
  #pragma unroll
  for (int mt = 0; mt < 2; ++mt) {
    #pragma unroll
    for (int q = 0; q < 16; ++q) {
      int cl = (q & 3) + 8 * (q >> 2) + 4 * lh;
      int c  = mt * 32 + cl;
      float qb = bq[c], sc = sb[c];
      #pragma unroll
      for (int nt = 0; nt < 2; ++nt) {
        int h = nt * 32 + lm;
        uint32_t xb = (uint32_t)(((ng + 1) * 8 + (c >> 3)) * 66 + (h + 1)) * 16u
                    + (uint32_t)(c & 7) * 2u;
        float xv = bf2f(*(const uint16_t*)(ldsx + swz(xb)));
        size_t idx = ((size_t)(b * 64 + c) * 16 + t) * 4096 + (size_t)w * 64 + h;
        out[idx] = g * (acc[mt][nt][q] + qb) * sc + xv;
      }
    }
  }
}

extern "C" void kernel_launch(void* const* d_in, const int* in_sizes, int n_in,
                              void* d_out, int out_size, void* d_ws, size_t ws_size,
                              hipStream_t stream) {
  const float* x   = (const float*)d_in[0];
  const float* wq  = (const float*)d_in[1];
  const float* wk  = (const float*)d_in[2];
  const float* wv  = (const float*)d_in[3];
  const float* bq  = (const float*)d_in[4];
  const float* bk  = (const float*)d_in[5];
  const float* bv  = (const float*)d_in[6];
  const float* gam = (const float*)d_in[7];

  uint16_t* wbf = (uint16_t*)d_ws;                    // 221184 B
  float* sbuf   = (float*)((uint8_t*)d_ws + 221184);  // 32 KB

  hipMemsetAsync(sbuf, 0, 8 * 16 * 64 * sizeof(float), stream);
  prep_weights<<<(110592 + 255) / 256, 256, 0, stream>>>(wq, wk, wv, wbf);
  kv_s_kernel<<<2048, 512, LDSX_BYTES + 16384, stream>>>(x, wbf + 36864, bk, bv, sbuf);
  q_out_kernel<<<2048, 256, LDSX_BYTES + 8192, stream>>>(x, wbf, bq, sbuf, gam, (float*)d_out);
}

// Round 16
// 156.225 us; speedup vs baseline: 1.0015x; 1.0015x over previous
//
#include <hip/hip_runtime.h>
#include <hip/hip_bf16.h>
#include <stdint.h>

typedef __attribute__((ext_vector_type(8))) short bf16x8;
typedef __attribute__((ext_vector_type(4))) float f32x4v;
typedef __attribute__((ext_vector_type(16))) float f32x16;

#define CH_STRIDE 65536  // T*W*H

__device__ __forceinline__ uint16_t f2bf(float f) {
  uint32_t u = __builtin_bit_cast(uint32_t, f);
  u = (u + 0x7FFFu + ((u >> 16) & 1u)) >> 16;
  return (uint16_t)u;
}
__device__ __forceinline__ float bf2f(uint32_t b) {
  return __builtin_bit_cast(float, b << 16);
}
__device__ __forceinline__ uint16_t cvt_bf(float f) {
  return __builtin_bit_cast(uint16_t, __float2bfloat16(f));
}

#define MFMA32(a, b, c) __builtin_amdgcn_mfma_f32_32x32x16_bf16(a, b, c, 0, 0, 0)
#define LGKM0 asm volatile("s_waitcnt lgkmcnt(0)" ::: "memory")
#define BAR __builtin_amdgcn_s_barrier()
#define SCHED0 __builtin_amdgcn_sched_barrier(0)

#define LDSX6  (6 * 8 * 66 * 16)   // 50688 (q kernel)
#define LDSX10 (10 * 8 * 66 * 16)  // 84480 (kv kernel)

__device__ __forceinline__ uint32_t swz(uint32_t b) {
  return b ^ (((b >> 7) & 7u) << 4);
}

__device__ __forceinline__ bf16x8 ldx(const uint8_t* ldsx, int row, int oct, int ci) {
  return *(const bf16x8*)(ldsx + swz((uint32_t)((row * 8 + oct) * 66 + ci) * 16u));
}

// staging unit: (row, oct, colgroup g) -> 8 dwordx4 loads, 4 swizzled b128 writes
__device__ __forceinline__ void stage_unit(uint8_t* ldsx, const float* xs, int w0, int u) {
  int row = u >> 7, oct = (u >> 4) & 7, g = u & 15;
  int w = w0 - 1 + row;
  uint32_t base = (uint32_t)((row * 8 + oct) * 66 + 4 * g + 1) * 16u;
  if ((unsigned)w < 64u) {
    const float* p = xs + (size_t)(oct * 8) * CH_STRIDE + w * 64 + 4 * g;
    f32x4v v[8];
    #pragma unroll
    for (int j = 0; j < 8; ++j) v[j] = *(const f32x4v*)(p + (size_t)j * CH_STRIDE);
    #pragma unroll
    for (int c = 0; c < 4; ++c) {
      bf16x8 frag;
      #pragma unroll
      for (int q = 0; q < 4; ++q) {
        frag[2 * q]     = (short)cvt_bf(v[2 * q][c]);
        frag[2 * q + 1] = (short)cvt_bf(v[2 * q + 1][c]);
      }
      *(bf16x8*)(ldsx + swz(base + (uint32_t)c * 16u)) = frag;
    }
  } else {
    bf16x8 z = {};
    #pragma unroll
    for (int c = 0; c < 4; ++c)
      *(bf16x8*)(ldsx + swz(base + (uint32_t)c * 16u)) = z;
  }
}
__device__ __forceinline__ void stage_halo(uint8_t* ldsx, int tid, int nrow) {
  if (tid < nrow * 16) {
    int row = tid >> 4, rem = tid & 15;
    int oct = rem >> 1, side = rem & 1;
    bf16x8 z = {};
    *(bf16x8*)(ldsx + swz((uint32_t)((row * 8 + oct) * 66 + side * 65) * 16u)) = z;
  }
}
__device__ __forceinline__ void stage_x256(uint8_t* ldsx, const float* xs, int w0, int tid) {
  stage_halo(ldsx, tid, 6);
  #pragma unroll
  for (int k = 0; k < 3; ++k) stage_unit(ldsx, xs, w0, tid + k * 256);
}
__device__ __forceinline__ void stage_x1024(uint8_t* ldsx, const float* xs, int w0, int tid) {
  stage_halo(ldsx, tid, 10);
  stage_unit(ldsx, xs, w0, tid);
  if (tid < 256) stage_unit(ldsx, xs, w0, 1024 + tid);
}

__device__ __forceinline__ bf16x8 ldw_kv(const uint8_t* ldsw, int oct, int rowloc) {
  return *(const bf16x8*)(ldsw + (uint32_t)(oct * 128 + rowloc) * 16u);
}
__device__ __forceinline__ bf16x8 ldw_q(const uint8_t* ldsw, int oct, int row) {
  return *(const bf16x8*)(ldsw + (uint32_t)(oct * 64 + row) * 16u);
}
__device__ __forceinline__ void ldw_g_q(bf16x8* r, const uint16_t* wq, int tap, int tid) {
  #pragma unroll
  for (int k = 0; k < 2; ++k)
    r[k] = *(const bf16x8*)(wq + ((size_t)tap * 512 + tid + k * 256) * 8);
}
__device__ __forceinline__ void stw_q(uint8_t* ldsw, const bf16x8* r, int tid) {
  #pragma unroll
  for (int k = 0; k < 2; ++k)
    *(bf16x8*)(ldsw + (uint32_t)(tid + k * 256) * 16u) = r[k];
}

// ---------------------------------------------------------------------------
__global__ void prep_weights(const float* __restrict__ wq, const float* __restrict__ wk,
                             const float* __restrict__ wv, uint16_t* __restrict__ wout) {
  int i = blockIdx.x * 256 + threadIdx.x;
  if (i >= 110592) return;
  if (i < 36864) {
    int tap = i >> 12, oct = (i >> 9) & 7, row = (i >> 3) & 63, j = i & 7;
    wout[i] = f2bf(wq[(row * 64 + oct * 8 + j) * 9 + tap]);
  } else {
    int m = i - 36864;
    int tap = m >> 13, oct = (m >> 10) & 7, rl = (m >> 3) & 127, j = m & 7;
    const float* src = (rl < 64) ? wk : wv;
    wout[i] = f2bf(src[((rl & 63) * 64 + oct * 8 + j) * 9 + tap]);
  }
}

// ---------------------------------------------------------------------------
// KV kernel: 1024 thr / 16 waves = (mg hi-bit, ng row 0-7); 8-row tile;
// double-buffered weight LDS -> ONE barrier per tap. r_pref ALWAYS holds
// tap+1's weights at write time (fixes R15's stale-register bug).
// ---------------------------------------------------------------------------
__global__ __launch_bounds__(1024, 4) void kv_s_kernel(
    const float* __restrict__ x, const uint16_t* __restrict__ wkv,
    const float* __restrict__ bk, const float* __restrict__ bv,
    float* __restrict__ s_out) {
  extern __shared__ uint8_t lds[];
  uint8_t* ldsx = lds;
  uint8_t* ldswA = lds + LDSX10;
  uint8_t* ldswB = lds + LDSX10 + 16384;
  const int tid = threadIdx.x;
  const int l = tid & 63;
  const int wid = tid >> 6;
  const int ng = wid & 7, mg = wid >> 3;
  int bid = (int)(blockIdx.x & 7) * 128 + (int)(blockIdx.x >> 3);  // XCD swizzle
  const int rg = bid & 7, slice = bid >> 3;
  const int b = slice >> 4, t = slice & 15;
  const int w0 = rg * 8;
  const float* xs = x + ((size_t)b * 1024 + t) * 4096;
  const int lm = l & 31, lh = l >> 5;

  stage_x1024(ldsx, xs, w0, tid);
  bf16x8 r_pref;
  r_pref = *(const bf16x8*)(wkv + (size_t)tid * 8);          // tap 0
  *(bf16x8*)(ldswA + (uint32_t)tid * 16u) = r_pref;          // vmcnt wait inserted
  r_pref = *(const bf16x8*)(wkv + ((size_t)1024 + tid) * 8); // tap 1, in flight
  SCHED0; LGKM0; BAR; SCHED0;

  f32x16 accK[2], accV[2];
  #pragma unroll
  for (int nt = 0; nt < 2; ++nt)
    #pragma unroll
    for (int q = 0; q < 16; ++q) { accK[nt][q] = 0.f; accV[nt][q] = 0.f; }

  #pragma unroll
  for (int tap = 0; tap < 9; ++tap) {
    const int dy = tap / 3, dx = tap % 3;
    const uint8_t* bufc = (tap & 1) ? ldswB : ldswA;
    uint8_t* bufn = (tap & 1) ? ldswA : ldswB;
    // s = 0 reads
    int oct0 = lh;
    bf16x8 aK = ldw_kv(bufc, oct0, mg * 32 + lm);
    bf16x8 aV = ldw_kv(bufc, oct0, 64 + mg * 32 + lm);
    bf16x8 b0 = ldx(ldsx, ng + dy, oct0, lm + dx);
    bf16x8 b1 = ldx(ldsx, ng + dy, oct0, 32 + lm + dx);
    // overlap: stage tap+1 into other buffer, issue tap+2 global load
    if (tap < 8) {
      *(bf16x8*)(bufn + (uint32_t)tid * 16u) = r_pref;       // tap+1 weights
      if (tap < 7)
        r_pref = *(const bf16x8*)(wkv + ((size_t)(tap + 2) * 1024 + tid) * 8);
    }
    __builtin_amdgcn_s_setprio(1);
    accK[0] = MFMA32(aK, b0, accK[0]);
    accK[1] = MFMA32(aK, b1, accK[1]);
    accV[0] = MFMA32(aV, b0, accV[0]);
    accV[1] = MFMA32(aV, b1, accV[1]);
    #pragma unroll
    for (int s = 1; s < 4; ++s) {
      int oct = s * 2 + lh;
      aK = ldw_kv(bufc, oct, mg * 32 + lm);
      aV = ldw_kv(bufc, oct, 64 + mg * 32 + lm);
      b0 = ldx(ldsx, ng + dy, oct, lm + dx);
      b1 = ldx(ldsx, ng + dy, oct, 32 + lm + dx);
      accK[0] = MFMA32(aK, b0, accK[0]);
      accK[1] = MFMA32(aK, b1, accK[1]);
      accV[0] = MFMA32(aV, b0, accV[0]);
      accV[1] = MFMA32(aV, b1, accV[1]);
    }
    __builtin_amdgcn_s_setprio(0);
    SCHED0; LGKM0; BAR; SCHED0;
  }

  // epilogue: LDS partial-dump, 64-thread reduce, 1 atomic per channel
  __syncthreads();
  float* red = (float*)lds;        // [c 64][260]
  #pragma unroll
  for (int q = 0; q < 16; ++q) {
    int cl = (q & 3) + 8 * (q >> 2) + 4 * lh;
    int c = mg * 32 + cl;
    float bkc = bk[c], bvc = bv[c];
    float p = (accK[0][q] + bkc) * (accV[0][q] + bvc)
            + (accK[1][q] + bkc) * (accV[1][q] + bvc);
    red[c * 260 + ng * 32 + lm] = p;
  }
  __syncthreads();
  if (tid < 64) {
    const f32x4v* rp = (const f32x4v*)(red + tid * 260);
    f32x4v a4 = {0.f, 0.f, 0.f, 0.f};
    #pragma unroll
    for (int j = 0; j < 64; ++j) a4 += rp[j];
    atomicAdd(s_out + (b * 16 + t) * 64 + tid, a4[0] + a4[1] + a4[2] + a4[3]);
  }
}

// ---------------------------------------------------------------------------
// Q kernel (R13/R14, unchanged — control).
// ---------------------------------------------------------------------------
__global__ __launch_bounds__(256, 2) void q_out_kernel(
    const float* __restrict__ x, const uint16_t* __restrict__ wq,
    const float* __restrict__ bq, const float* __restrict__ s_in,
    const float* __restrict__ gamma, float* __restrict__ out) {
  extern __shared__ uint8_t lds[];
  uint8_t* ldsx = lds;
  uint8_t* ldsw = lds + LDSX6;
  const int tid = threadIdx.x;
  const int l = tid & 63, ng = tid >> 6;
  int bid = (int)(blockIdx.x & 7) * 256 + (int)(blockIdx.x >> 3);  // XCD swizzle
  const int rg = bid & 15, slice = bid >> 4;
  const int b = slice >> 4, t = slice & 15;
  const int w0 = rg * 4;
  const float* xs = x + ((size_t)b * 1024 + t) * 4096;
  const int lm = l & 31, lh = l >> 5;

  stage_x256(ldsx, xs, w0, tid);
  bf16x8 r[2];
  ldw_g_q(r, wq, 0, tid);
  stw_q(ldsw, r, tid);
  ldw_g_q(r, wq, 1, tid);
  SCHED0; LGKM0; BAR; SCHED0;

  f32x16 acc[2][2];
  #pragma unroll
  for (int mt = 0; mt < 2; ++mt)
    #pragma unroll
    for (int nt = 0; nt < 2; ++nt)
      #pragma unroll
      for (int q = 0; q < 16; ++q) acc[mt][nt][q] = 0.f;

  #pragma unroll
  for (int tap = 0; tap < 9; ++tap) {
    const int dy = tap / 3, dx = tap % 3;
    __builtin_amdgcn_s_setprio(1);
    #pragma unroll
    for (int s = 0; s < 4; ++s) {
      int oct = s * 2 + lh;
      bf16x8 a0 = ldw_q(ldsw, oct, lm);
      bf16x8 a1 = ldw_q(ldsw, oct, 32 + lm);
      bf16x8 b0 = ldx(ldsx, ng + dy, oct, lm + dx);
      bf16x8 b1 = ldx(ldsx, ng + dy, oct, 32 + lm + dx);
      acc[0][0] = MFMA32(a0, b0, acc[0][0]);
      acc[0][1] = MFMA32(a0, b1, acc[0][1]);
      acc[1][0] = MFMA32(a1, b0, acc[1][0]);
      acc[1][1] = MFMA32(a1, b1, acc[1][1]);
    }
    __builtin_amdgcn_s_setprio(0);
    if (tap < 8) {
      SCHED0; BAR;
      stw_q(ldsw, r, tid);
      if (tap < 7) ldw_g_q(r, wq, tap + 2, tid);
      SCHED0; LGKM0; BAR; SCHED0;
    }
  }

  float g = gamma[0];
  const float* sb = s_in + (b * 16 + t) * 64;
  int w = w0 + ng;
  #pragma unroll
  for (int mt = 0; mt < 2; ++mt) {
    #pragma unroll
    for (int q = 0; q < 16; ++q) {
      int cl = (q & 3) + 8 * (q >> 2) + 4 * lh;
      int c  = mt * 32 + cl;
      float qb = bq[c], sc = sb[c];
      #pragma unroll
      for (int nt = 0; nt < 2; ++nt) {
        int h = nt * 32 + lm;
        uint32_t xb = (uint32_t)(((ng + 1) * 8 + (c >> 3)) * 66 + (h + 1)) * 16u
                    + (uint32_t)(c & 7) * 2u;
        float xv = bf2f(*(const uint16_t*)(ldsx + swz(xb)));
        size_t idx = ((size_t)(b * 64 + c) * 16 + t) * 4096 + (size_t)w * 64 + h;
        out[idx] = g * (acc[mt][nt][q] + qb) * sc + xv;
      }
    }
  }
}

extern "C" void kernel_launch(void* const* d_in, const int* in_sizes, int n_in,
                              void* d_out, int out_size, void* d_ws, size_t ws_size,
                              hipStream_t stream) {
  const float* x   = (const float*)d_in[0];
  const float* wq  = (const float*)d_in[1];
  const float* wk  = (const float*)d_in[2];
  const float* wv  = (const float*)d_in[3];
  const float* bq  = (const float*)d_in[4];
  const float* bk  = (const float*)d_in[5];
  const float* bv  = (const float*)d_in[6];
  const float* gam = (const float*)d_in[7];

  uint16_t* wbf = (uint16_t*)d_ws;                    // 221184 B
  float* sbuf   = (float*)((uint8_t*)d_ws + 221184);  // 32 KB

  hipMemsetAsync(sbuf, 0, 8 * 16 * 64 * sizeof(float), stream);
  prep_weights<<<(110592 + 255) / 256, 256, 0, stream>>>(wq, wk, wv, wbf);
  kv_s_kernel<<<1024, 1024, LDSX10 + 32768, stream>>>(x, wbf + 36864, bk, bv, sbuf);
  q_out_kernel<<<2048, 256, LDSX6 + 8192, stream>>>(x, wbf, bq, sbuf, gam, (float*)d_out);
}